// Round 1
// baseline (1635.645 us; speedup 1.0000x reference)
//
#include <hip/hip_runtime.h>

#define PP 96
#define NB (PP*PP)          // 9216 boxes
#define NMS_CAP 2048        // LDS staging capacity for sorted boxes
#define PROB_THR 0.9f
#define IOU_THR 0.5f

// ---------------------------------------------------------------------------
// Kernel A: per-box decode + compaction of valid (score > 0.9) boxes.
// Exact float semantics: *16 is a power-of-2 (exact); adds/rounds done with
// _rn intrinsics to forbid FMA contraction; rintf == round-half-to-even
// (matches jnp.round / numpy).
// ---------------------------------------------------------------------------
__global__ void k_compute(const float* __restrict__ x, int* __restrict__ counter,
                          float* __restrict__ cs,
                          float* __restrict__ cx1, float* __restrict__ cy1,
                          float* __restrict__ cx2, float* __restrict__ cy2,
                          int* __restrict__ cidx)
{
    int n = blockIdx.x * blockDim.x + threadIdx.x;
    if (n >= NB) return;
    float s = x[n];                      // plane 0: prob
    if (!(s > PROB_THR)) return;
    float xv = x[NB + n];
    float yv = x[2 * NB + n];
    float wv = x[3 * NB + n];
    float hv = x[4 * NB + n];
    int i = n / PP;
    int j = n - i * PP;
    float bx = __fadd_rn(__fmul_rn(xv, 16.0f), (float)i * 16.0f);
    float by = __fadd_rn(__fmul_rn(yv, 16.0f), (float)j * 16.0f);
    float bw = __fmul_rn(wv, 1536.0f);
    float bh = __fmul_rn(hv, 1536.0f);
    float X1 = rintf(bx);
    float Y1 = rintf(by);
    float X2 = rintf(__fadd_rn(bw, bx));   // round(bw + bx), numpy order
    float Y2 = rintf(__fadd_rn(bh, by));
    int pos = atomicAdd(counter, 1);
    cs[pos] = s; cx1[pos] = X1; cy1[pos] = Y1; cx2[pos] = X2; cy2[pos] = Y2;
    cidx[pos] = n;
}

// ---------------------------------------------------------------------------
// Kernel B: deterministic rank of each compacted box under the total order
// (score desc, original index asc) == stable argsort(-key); scatter to sorted
// arrays. M ~ 922 so the O(M^2) count is trivial (reads hit L1/L2).
// ---------------------------------------------------------------------------
__global__ void k_rank(const int* __restrict__ counter,
                       const float* __restrict__ cs,
                       const float* __restrict__ cx1, const float* __restrict__ cy1,
                       const float* __restrict__ cx2, const float* __restrict__ cy2,
                       const int* __restrict__ cidx,
                       float* __restrict__ ss,
                       float* __restrict__ sx1, float* __restrict__ sy1,
                       float* __restrict__ sx2, float* __restrict__ sy2)
{
    int t = blockIdx.x * blockDim.x + threadIdx.x;
    int M = *counter; if (M > NB) M = NB;
    if (t >= M) return;
    float s = cs[t];
    int id = cidx[t];
    int r = 0;
    for (int q = 0; q < M; ++q) {
        float sq = cs[q];
        int iq = cidx[q];
        r += (sq > s || (sq == s && iq < id)) ? 1 : 0;
    }
    ss[r] = s; sx1[r] = cx1[t]; sy1[r] = cy1[t]; sx2[r] = cx2[t]; sy2[r] = cy2[t];
}

// ---------------------------------------------------------------------------
// Kernel C: single-wave greedy NMS + output write.
// Lane l owns sorted indices j with (j % 64 == l); kept flags are per-lane
// register bitsets (bit k <-> j = l + 64k, k < 144). Suppression decision is
// a wave-uniform __any() — no barriers in the sequential loop. Boxes staged
// in LDS (M <= NMS_CAP; global fallback otherwise). Non-kept rows stay zero
// (d_out memset on the stream beforehand).
// IoU exactly mirrors numpy: inter & areas are exact ints (< 2^24); union is
// (ai + aj) - inter with single roundings; IEEE division.
// ---------------------------------------------------------------------------
__global__ void __launch_bounds__(64) k_nms(const int* __restrict__ counter,
        const float* __restrict__ ss,
        const float* __restrict__ sx1, const float* __restrict__ sy1,
        const float* __restrict__ sx2, const float* __restrict__ sy2,
        float* __restrict__ out)
{
    __shared__ float lx1[NMS_CAP], ly1[NMS_CAP], lx2[NMS_CAP], ly2[NMS_CAP], lar[NMS_CAP];
    int M = *counter; if (M > NB) M = NB;
    int lane = threadIdx.x;

    for (int k = lane; k < M && k < NMS_CAP; k += 64) {
        float a = sx1[k], b = sy1[k], c = sx2[k], d = sy2[k];
        lx1[k] = a; ly1[k] = b; lx2[k] = c; ly2[k] = d;
        lar[k] = __fmul_rn(__fsub_rn(c, a), __fsub_rn(d, b));
    }
    __syncthreads();

    unsigned long long kb[3] = {0ull, 0ull, 0ull};   // per-lane kept bits

    for (int i = 0; i < M; ++i) {
        float ix1, iy1, ix2, iy2, iar;
        if (i < NMS_CAP) { ix1 = lx1[i]; iy1 = ly1[i]; ix2 = lx2[i]; iy2 = ly2[i]; iar = lar[i]; }
        else {
            ix1 = sx1[i]; iy1 = sy1[i]; ix2 = sx2[i]; iy2 = sy2[i];
            iar = __fmul_rn(__fsub_rn(ix2, ix1), __fsub_rn(iy2, iy1));
        }
        int hit = 0;
        int nk = (i > lane) ? ((i - lane + 63) >> 6) : 0;  // #k with lane+64k < i
        for (int w = 0; w < 3 && !hit; ++w) {
            int klim = nk - (w << 6);
            if (klim <= 0) break;
            unsigned long long bits = kb[w];
            if (klim < 64) bits &= ((1ull << klim) - 1ull);
            while (bits) {
                int kk = __builtin_ctzll(bits);
                bits &= bits - 1ull;
                int jj = lane + (((w << 6) + kk) << 6);
                float jx1, jy1, jx2, jy2, jar;
                if (jj < NMS_CAP) { jx1 = lx1[jj]; jy1 = ly1[jj]; jx2 = lx2[jj]; jy2 = ly2[jj]; jar = lar[jj]; }
                else {
                    jx1 = sx1[jj]; jy1 = sy1[jj]; jx2 = sx2[jj]; jy2 = sy2[jj];
                    jar = __fmul_rn(__fsub_rn(jx2, jx1), __fsub_rn(jy2, jy1));
                }
                float xx1 = fmaxf(ix1, jx1), yy1 = fmaxf(iy1, jy1);
                float xx2 = fminf(ix2, jx2), yy2 = fminf(iy2, jy2);
                float iw = fmaxf(__fsub_rn(xx2, xx1), 0.0f);
                float ih = fmaxf(__fsub_rn(yy2, yy1), 0.0f);
                float inter = __fmul_rn(iw, ih);
                float uni = __fsub_rn(__fadd_rn(iar, jar), inter);
                if (uni > 0.0f && __fdiv_rn(inter, uni) > IOU_THR) { hit = 1; break; }
            }
        }
        int suppressed = __any(hit);
        if (!suppressed && lane == (i & 63)) {
            int k = i >> 6;
            kb[k >> 6] |= 1ull << (k & 63);
        }
    }

    // Emit kept rows: [score, x1, y1, x2-x1, y2-y1]; keeps flag as 1.0f.
    for (int w = 0; w < 3; ++w) {
        unsigned long long bits = kb[w];
        while (bits) {
            int kk = __builtin_ctzll(bits);
            bits &= bits - 1ull;
            int jj = lane + (((w << 6) + kk) << 6);
            float a, b, c, d;
            if (jj < NMS_CAP) { a = lx1[jj]; b = ly1[jj]; c = lx2[jj]; d = ly2[jj]; }
            else { a = sx1[jj]; b = sy1[jj]; c = sx2[jj]; d = sy2[jj]; }
            out[jj * 5 + 0] = ss[jj];
            out[jj * 5 + 1] = a;
            out[jj * 5 + 2] = b;
            out[jj * 5 + 3] = __fsub_rn(c, a);
            out[jj * 5 + 4] = __fsub_rn(d, b);
            out[5 * NB + jj] = 1.0f;
        }
    }
}

extern "C" void kernel_launch(void* const* d_in, const int* in_sizes, int n_in,
                              void* d_out, int out_size, void* d_ws, size_t ws_size,
                              hipStream_t stream) {
    const float* x = (const float*)d_in[0];
    float* out = (float*)d_out;

    // Workspace layout (d_ws is re-poisoned 0xAA before every call):
    // [0,16)            : counter (int, padded)
    // base + 0*NB .. 5*NB : compacted score,x1,y1,x2,y2 ; cidx (int)
    // base + 6*NB .. 11*NB: sorted score,x1,y1,x2,y2
    char* ws = (char*)d_ws;
    int* counter = (int*)ws;
    float* base = (float*)(ws + 16);
    float* cs  = base;
    float* cx1 = base + 1 * NB;
    float* cy1 = base + 2 * NB;
    float* cx2 = base + 3 * NB;
    float* cy2 = base + 4 * NB;
    int*   cidx = (int*)(base + 5 * NB);
    float* ss  = base + 6 * NB;
    float* sx1 = base + 7 * NB;
    float* sy1 = base + 8 * NB;
    float* sx2 = base + 9 * NB;
    float* sy2 = base + 10 * NB;

    hipMemsetAsync(d_out, 0, (size_t)out_size * sizeof(float), stream);
    hipMemsetAsync(counter, 0, 16, stream);

    const int threads = 256;
    const int blocks = (NB + threads - 1) / threads;   // 36
    k_compute<<<blocks, threads, 0, stream>>>(x, counter, cs, cx1, cy1, cx2, cy2, cidx);
    k_rank<<<blocks, threads, 0, stream>>>(counter, cs, cx1, cy1, cx2, cy2, cidx,
                                           ss, sx1, sy1, sx2, sy2);
    k_nms<<<1, 64, 0, stream>>>(counter, ss, sx1, sy1, sx2, sy2, out);
}

// Round 2
// 397.047 us; speedup vs baseline: 4.1195x; 4.1195x over previous
//
#include <hip/hip_runtime.h>

#define PP 96
#define NB (PP*PP)          // 9216 boxes
#define NMS_CAP 2048        // LDS staging capacity (slow-path only)
#define FAST_MAX_M 4096     // fast bitmask sweep handles M <= 4096 (W <= 64)
#define PROB_THR 0.9f
#define IOU_THR 0.5f

// ---------------------------------------------------------------------------
// Kernel A: per-box decode + compaction of valid (score > 0.9) boxes.
// ---------------------------------------------------------------------------
__global__ void k_compute(const float* __restrict__ x, int* __restrict__ counter,
                          float* __restrict__ cs,
                          float* __restrict__ cx1, float* __restrict__ cy1,
                          float* __restrict__ cx2, float* __restrict__ cy2,
                          int* __restrict__ cidx)
{
    int n = blockIdx.x * blockDim.x + threadIdx.x;
    if (n >= NB) return;
    float s = x[n];                      // plane 0: prob
    if (!(s > PROB_THR)) return;
    float xv = x[NB + n];
    float yv = x[2 * NB + n];
    float wv = x[3 * NB + n];
    float hv = x[4 * NB + n];
    int i = n / PP;
    int j = n - i * PP;
    float bx = __fadd_rn(__fmul_rn(xv, 16.0f), (float)i * 16.0f);
    float by = __fadd_rn(__fmul_rn(yv, 16.0f), (float)j * 16.0f);
    float bw = __fmul_rn(wv, 1536.0f);
    float bh = __fmul_rn(hv, 1536.0f);
    float X1 = rintf(bx);
    float Y1 = rintf(by);
    float X2 = rintf(__fadd_rn(bw, bx));   // round(bw + bx), numpy order
    float Y2 = rintf(__fadd_rn(bh, by));
    int pos = atomicAdd(counter, 1);
    cs[pos] = s; cx1[pos] = X1; cy1[pos] = Y1; cx2[pos] = X2; cy2[pos] = Y2;
    cidx[pos] = n;
}

// ---------------------------------------------------------------------------
// Kernel B: deterministic rank under (score desc, original index asc) ==
// stable argsort(-key); scatter to sorted arrays.
// ---------------------------------------------------------------------------
__global__ void k_rank(const int* __restrict__ counter,
                       const float* __restrict__ cs,
                       const float* __restrict__ cx1, const float* __restrict__ cy1,
                       const float* __restrict__ cx2, const float* __restrict__ cy2,
                       const int* __restrict__ cidx,
                       float* __restrict__ ss,
                       float* __restrict__ sx1, float* __restrict__ sy1,
                       float* __restrict__ sx2, float* __restrict__ sy2)
{
    int t = blockIdx.x * blockDim.x + threadIdx.x;
    int M = *counter; if (M > NB) M = NB;
    if (t >= M) return;
    float s = cs[t];
    int id = cidx[t];
    int r = 0;
    for (int q = 0; q < M; ++q) {
        float sq = cs[q];
        int iq = cidx[q];
        r += (sq > s || (sq == s && iq < id)) ? 1 : 0;
    }
    ss[r] = s; sx1[r] = cx1[t]; sy1[r] = cy1[t]; sx2[r] = cx2[t]; sy2[r] = cy2[t];
}

// ---------------------------------------------------------------------------
// Device IoU — exactly mirrors the numpy arithmetic/order (no FMA).
// ---------------------------------------------------------------------------
__device__ __forceinline__ int iou_hit(float ix1, float iy1, float ix2, float iy2, float iar,
                                       float jx1, float jy1, float jx2, float jy2, float jar)
{
    float xx1 = fmaxf(ix1, jx1), yy1 = fmaxf(iy1, jy1);
    float xx2 = fminf(ix2, jx2), yy2 = fminf(iy2, jy2);
    float iw = fmaxf(__fsub_rn(xx2, xx1), 0.0f);
    float ih = fmaxf(__fsub_rn(yy2, yy1), 0.0f);
    float inter = __fmul_rn(iw, ih);
    float uni = __fsub_rn(__fadd_rn(iar, jar), inter);
    return (uni > 0.0f && __fdiv_rn(inter, uni) > IOU_THR) ? 1 : 0;
}

// ---------------------------------------------------------------------------
// Kernel C: adjacency build. One 64-thread block per sorted row i; lane
// computes IoU(i, j) for j = k*64 + lane and __ballot packs 64 bits/word.
// Row stride W = ceil(M/64) u64 words. Only runs on the fast path.
// ---------------------------------------------------------------------------
__global__ void __launch_bounds__(64) k_adj(const int* __restrict__ counter,
        const float* __restrict__ sx1, const float* __restrict__ sy1,
        const float* __restrict__ sx2, const float* __restrict__ sy2,
        unsigned long long* __restrict__ adj, long long cap_words)
{
    int M = *counter; if (M > NB) M = NB;
    int W = (M + 63) >> 6;
    if (M > FAST_MAX_M || (long long)M * W > cap_words) return;   // slow path owns it
    int i = blockIdx.x;
    if (i >= M) return;
    int lane = threadIdx.x;
    float ix1 = sx1[i], iy1 = sy1[i], ix2 = sx2[i], iy2 = sy2[i];
    float iar = __fmul_rn(__fsub_rn(ix2, ix1), __fsub_rn(iy2, iy1));
    for (int k = 0; k < W; ++k) {
        int j = (k << 6) + lane;
        int hit = 0;
        if (j < M) {
            float jx1 = sx1[j], jy1 = sy1[j], jx2 = sx2[j], jy2 = sy2[j];
            float jar = __fmul_rn(__fsub_rn(jx2, jx1), __fsub_rn(jy2, jy1));
            hit = iou_hit(ix1, iy1, ix2, iy2, iar, jx1, jy1, jx2, jy2, jar);
        }
        unsigned long long m = __ballot(hit);
        if (lane == 0) adj[(size_t)i * W + k] = m;
    }
}

// ---------------------------------------------------------------------------
// Kernel D: single-wave sweep.
// FAST (M <= 4096): lane w owns suppression word w. Per i: broadcast word
// i>>6, test bit, if kept OR in the (prefetched) adjacency row. Kept bits
// recorded at decision time (final sup mask is NOT the keep mask — later
// rows can set bit i after i was already kept).
// SLOW fallback (adjacency doesn't fit): previous on-the-fly IoU loop.
// ---------------------------------------------------------------------------
__global__ void __launch_bounds__(64) k_sweep(const int* __restrict__ counter,
        const float* __restrict__ ss,
        const float* __restrict__ sx1, const float* __restrict__ sy1,
        const float* __restrict__ sx2, const float* __restrict__ sy2,
        const unsigned long long* __restrict__ adj, long long cap_words,
        float* __restrict__ out)
{
    int M = *counter; if (M > NB) M = NB;
    int W = (M + 63) >> 6;
    int lane = threadIdx.x;

    bool fast = (M <= FAST_MAX_M) && ((long long)M * W <= cap_words);

    if (fast) {
        unsigned long long sup = 0ull, kb = 0ull;
        unsigned long long cur = (lane < W && M > 0) ? adj[lane] : 0ull;
        for (int i = 0; i < M; ++i) {
            unsigned long long nxt = 0ull;                 // prefetch row i+1
            if (i + 1 < M && lane < W) nxt = adj[(size_t)(i + 1) * W + lane];
            unsigned long long supw = __shfl(sup, i >> 6);
            if (!((supw >> (i & 63)) & 1ull)) {
                if (lane == (i & 63)) kb |= 1ull << (i >> 6);
                sup |= cur;
            }
            cur = nxt;
        }
        // Emit kept rows: i = (bit << 6) + lane
        while (kb) {
            int k = __builtin_ctzll(kb);
            kb &= kb - 1ull;
            int i = (k << 6) + lane;
            float a = sx1[i], b = sy1[i], c = sx2[i], d = sy2[i];
            out[i * 5 + 0] = ss[i];
            out[i * 5 + 1] = a;
            out[i * 5 + 2] = b;
            out[i * 5 + 3] = __fsub_rn(c, a);
            out[i * 5 + 4] = __fsub_rn(d, b);
            out[5 * NB + i] = 1.0f;
        }
        return;
    }

    // ---------------- slow fallback (correct for any M <= NB) ----------------
    __shared__ float lx1[NMS_CAP], ly1[NMS_CAP], lx2[NMS_CAP], ly2[NMS_CAP], lar[NMS_CAP];
    for (int k = lane; k < M && k < NMS_CAP; k += 64) {
        float a = sx1[k], b = sy1[k], c = sx2[k], d = sy2[k];
        lx1[k] = a; ly1[k] = b; lx2[k] = c; ly2[k] = d;
        lar[k] = __fmul_rn(__fsub_rn(c, a), __fsub_rn(d, b));
    }
    __syncthreads();

    unsigned long long kbs[3] = {0ull, 0ull, 0ull};
    for (int i = 0; i < M; ++i) {
        float ix1, iy1, ix2, iy2, iar;
        if (i < NMS_CAP) { ix1 = lx1[i]; iy1 = ly1[i]; ix2 = lx2[i]; iy2 = ly2[i]; iar = lar[i]; }
        else {
            ix1 = sx1[i]; iy1 = sy1[i]; ix2 = sx2[i]; iy2 = sy2[i];
            iar = __fmul_rn(__fsub_rn(ix2, ix1), __fsub_rn(iy2, iy1));
        }
        int hit = 0;
        int nk = (i > lane) ? ((i - lane + 63) >> 6) : 0;
        for (int w = 0; w < 3 && !hit; ++w) {
            int klim = nk - (w << 6);
            if (klim <= 0) break;
            unsigned long long bits = kbs[w];
            if (klim < 64) bits &= ((1ull << klim) - 1ull);
            while (bits) {
                int kk = __builtin_ctzll(bits);
                bits &= bits - 1ull;
                int jj = lane + (((w << 6) + kk) << 6);
                float jx1, jy1, jx2, jy2, jar;
                if (jj < NMS_CAP) { jx1 = lx1[jj]; jy1 = ly1[jj]; jx2 = lx2[jj]; jy2 = ly2[jj]; jar = lar[jj]; }
                else {
                    jx1 = sx1[jj]; jy1 = sy1[jj]; jx2 = sx2[jj]; jy2 = sy2[jj];
                    jar = __fmul_rn(__fsub_rn(jx2, jx1), __fsub_rn(jy2, jy1));
                }
                if (iou_hit(ix1, iy1, ix2, iy2, iar, jx1, jy1, jx2, jy2, jar)) { hit = 1; break; }
            }
        }
        int suppressed = __any(hit);
        if (!suppressed && lane == (i & 63)) {
            int k = i >> 6;
            kbs[k >> 6] |= 1ull << (k & 63);
        }
    }
    for (int w = 0; w < 3; ++w) {
        unsigned long long bits = kbs[w];
        while (bits) {
            int kk = __builtin_ctzll(bits);
            bits &= bits - 1ull;
            int jj = lane + (((w << 6) + kk) << 6);
            float a, b, c, d;
            if (jj < NMS_CAP) { a = lx1[jj]; b = ly1[jj]; c = lx2[jj]; d = ly2[jj]; }
            else { a = sx1[jj]; b = sy1[jj]; c = sx2[jj]; d = sy2[jj]; }
            out[jj * 5 + 0] = ss[jj];
            out[jj * 5 + 1] = a;
            out[jj * 5 + 2] = b;
            out[jj * 5 + 3] = __fsub_rn(c, a);
            out[jj * 5 + 4] = __fsub_rn(d, b);
            out[5 * NB + jj] = 1.0f;
        }
    }
}

extern "C" void kernel_launch(void* const* d_in, const int* in_sizes, int n_in,
                              void* d_out, int out_size, void* d_ws, size_t ws_size,
                              hipStream_t stream) {
    const float* x = (const float*)d_in[0];
    float* out = (float*)d_out;

    // Workspace layout:
    // [0,16)                 : counter
    // base + 0..5*NB         : compacted s,x1,y1,x2,y2 ; cidx
    // base + 6..10*NB        : sorted s,x1,y1,x2,y2
    // adj_off ..             : adjacency bit matrix (M rows x W u64 words)
    char* ws = (char*)d_ws;
    int* counter = (int*)ws;
    float* base = (float*)(ws + 16);
    float* cs  = base;
    float* cx1 = base + 1 * NB;
    float* cy1 = base + 2 * NB;
    float* cx2 = base + 3 * NB;
    float* cy2 = base + 4 * NB;
    int*   cidx = (int*)(base + 5 * NB);
    float* ss  = base + 6 * NB;
    float* sx1 = base + 7 * NB;
    float* sy1 = base + 8 * NB;
    float* sx2 = base + 9 * NB;
    float* sy2 = base + 10 * NB;
    size_t adj_off = 16 + (size_t)11 * NB * 4;          // 405,520 B (8-aligned)
    unsigned long long* adj = (unsigned long long*)(ws + adj_off);
    long long cap_words = (ws_size > adj_off) ? (long long)((ws_size - adj_off) / 8) : 0;

    hipMemsetAsync(d_out, 0, (size_t)out_size * sizeof(float), stream);
    hipMemsetAsync(counter, 0, 16, stream);

    const int threads = 256;
    const int blocks = (NB + threads - 1) / threads;   // 36
    k_compute<<<blocks, threads, 0, stream>>>(x, counter, cs, cx1, cy1, cx2, cy2, cidx);
    k_rank<<<blocks, threads, 0, stream>>>(counter, cs, cx1, cy1, cx2, cy2, cidx,
                                           ss, sx1, sy1, sx2, sy2);
    k_adj<<<NB, 64, 0, stream>>>(counter, sx1, sy1, sx2, sy2, adj, cap_words);
    k_sweep<<<1, 64, 0, stream>>>(counter, ss, sx1, sy1, sx2, sy2, adj, cap_words, out);
}

// Round 3
// 174.233 us; speedup vs baseline: 9.3877x; 2.2788x over previous
//
#include <hip/hip_runtime.h>

#define PP 96
#define NB (PP*PP)          // 9216 boxes
#define NMS_CAP 2048        // LDS staging capacity (slow-path only)
#define FAST_MAX_M 4096     // fast bitmask sweep handles M <= 4096 (W <= 64)
#define PROB_THR 0.9f
#define IOU_THR 0.5f
#define RANK_TILE 2048

typedef unsigned long long u64;

// ---------------------------------------------------------------------------
// Kernel Z: zero d_out + counter in one dispatch (replaces two memsets).
// ---------------------------------------------------------------------------
__global__ void k_zero(float* __restrict__ out, int out_size, int* __restrict__ counter)
{
    int t = blockIdx.x * blockDim.x + threadIdx.x;
    if (t == 0) { counter[0] = 0; }
    for (int i = t * 4; i < out_size; i += gridDim.x * blockDim.x * 4) {
        if (i + 3 < out_size) *(float4*)(out + i) = make_float4(0.f, 0.f, 0.f, 0.f);
        else for (int k = i; k < out_size; ++k) out[k] = 0.f;
    }
}

// ---------------------------------------------------------------------------
// Kernel A: decode + compact valid (score > 0.9) boxes. Writes a packed sort
// key: (bits(score) << 32) | (NB-1-idx). Scores are positive so float-bit
// compare == float compare; tie-break = smaller original index first.
// ---------------------------------------------------------------------------
__global__ void k_compute(const float* __restrict__ x, int* __restrict__ counter,
                          u64* __restrict__ ckey,
                          float* __restrict__ cx1, float* __restrict__ cy1,
                          float* __restrict__ cx2, float* __restrict__ cy2)
{
    int n = blockIdx.x * blockDim.x + threadIdx.x;
    if (n >= NB) return;
    float s = x[n];
    if (!(s > PROB_THR)) return;
    float xv = x[NB + n];
    float yv = x[2 * NB + n];
    float wv = x[3 * NB + n];
    float hv = x[4 * NB + n];
    int i = n / PP;
    int j = n - i * PP;
    float bx = __fadd_rn(__fmul_rn(xv, 16.0f), (float)i * 16.0f);
    float by = __fadd_rn(__fmul_rn(yv, 16.0f), (float)j * 16.0f);
    float bw = __fmul_rn(wv, 1536.0f);
    float bh = __fmul_rn(hv, 1536.0f);
    float X1 = rintf(bx);
    float Y1 = rintf(by);
    float X2 = rintf(__fadd_rn(bw, bx));
    float Y2 = rintf(__fadd_rn(bh, by));
    int pos = atomicAdd(counter, 1);
    ckey[pos] = ((u64)__float_as_uint(s) << 32) | (u64)(NB - 1 - n);
    cx1[pos] = X1; cy1[pos] = Y1; cx2[pos] = X2; cy2[pos] = Y2;
}

// ---------------------------------------------------------------------------
// Kernel B: rank via counting sort over packed keys, LDS-tiled.
// rank(t) = #{q : key_q > key_t}; keys unique -> permutation. Scatter sorted.
// ---------------------------------------------------------------------------
__global__ void __launch_bounds__(256) k_rank(const int* __restrict__ counter,
                       const u64* __restrict__ ckey,
                       const float* __restrict__ cx1, const float* __restrict__ cy1,
                       const float* __restrict__ cx2, const float* __restrict__ cy2,
                       float* __restrict__ ss,
                       float* __restrict__ sx1, float* __restrict__ sy1,
                       float* __restrict__ sx2, float* __restrict__ sy2)
{
    __shared__ u64 lk[RANK_TILE];
    int M = *counter; if (M > NB) M = NB;
    int t = blockIdx.x * 256 + threadIdx.x;
    u64 mykey = (t < M) ? ckey[t] : 0ull;
    int r = 0;
    for (int q0 = 0; q0 < M; q0 += RANK_TILE) {
        int cnt = M - q0; if (cnt > RANK_TILE) cnt = RANK_TILE;
        __syncthreads();
        for (int q = threadIdx.x; q < cnt; q += 256) lk[q] = ckey[q0 + q];
        __syncthreads();
        if (t < M) {
            #pragma unroll 8
            for (int q = 0; q < cnt; ++q) r += (lk[q] > mykey) ? 1 : 0;
        }
    }
    if (t < M) {
        ss[r]  = __uint_as_float((unsigned)(mykey >> 32));
        sx1[r] = cx1[t]; sy1[r] = cy1[t]; sx2[r] = cx2[t]; sy2[r] = cy2[t];
    }
}

// ---------------------------------------------------------------------------
// Device IoU — exactly mirrors the numpy arithmetic/order (no FMA).
// ---------------------------------------------------------------------------
__device__ __forceinline__ int iou_hit(float ix1, float iy1, float ix2, float iy2, float iar,
                                       float jx1, float jy1, float jx2, float jy2, float jar)
{
    float xx1 = fmaxf(ix1, jx1), yy1 = fmaxf(iy1, jy1);
    float xx2 = fminf(ix2, jx2), yy2 = fminf(iy2, jy2);
    float iw = fmaxf(__fsub_rn(xx2, xx1), 0.0f);
    float ih = fmaxf(__fsub_rn(yy2, yy1), 0.0f);
    float inter = __fmul_rn(iw, ih);
    float uni = __fsub_rn(__fadd_rn(iar, jar), inter);
    return (uni > 0.0f && __fdiv_rn(inter, uni) > IOU_THR) ? 1 : 0;
}

__device__ __forceinline__ bool fast_ok(int M, long long cap_words)
{
    long long W = (M + 63) >> 6;
    long long R = (long long)(((M + 31) >> 5) << 5);
    return (M <= FAST_MAX_M) && (R * W <= cap_words);
}

// ---------------------------------------------------------------------------
// Kernel C: adjacency build, 4 rows per 64-thread block (j-box loads shared).
// ---------------------------------------------------------------------------
__global__ void __launch_bounds__(64) k_adj(const int* __restrict__ counter,
        const float* __restrict__ sx1, const float* __restrict__ sy1,
        const float* __restrict__ sx2, const float* __restrict__ sy2,
        u64* __restrict__ adj, long long cap_words)
{
    int M = *counter; if (M > NB) M = NB;
    if (!fast_ok(M, cap_words)) return;      // slow path owns it
    int W = (M + 63) >> 6;
    int i0 = blockIdx.x << 2;
    if (i0 >= M) return;
    int lane = threadIdx.x;
    int nr = M - i0; if (nr > 4) nr = 4;
    float ix1[4], iy1[4], ix2[4], iy2[4], iar[4];
    #pragma unroll
    for (int r = 0; r < 4; ++r) {
        int i = i0 + ((r < nr) ? r : 0);
        ix1[r] = sx1[i]; iy1[r] = sy1[i]; ix2[r] = sx2[i]; iy2[r] = sy2[i];
        iar[r] = __fmul_rn(__fsub_rn(ix2[r], ix1[r]), __fsub_rn(iy2[r], iy1[r]));
    }
    for (int k = 0; k < W; ++k) {
        int j = (k << 6) + lane;
        int inb = (j < M);
        int jc = inb ? j : (M - 1);
        float jx1 = sx1[jc], jy1 = sy1[jc], jx2 = sx2[jc], jy2 = sy2[jc];
        float jar = __fmul_rn(__fsub_rn(jx2, jx1), __fsub_rn(jy2, jy1));
        int h[4];
        #pragma unroll
        for (int r = 0; r < 4; ++r)
            h[r] = inb && iou_hit(ix1[r], iy1[r], ix2[r], iy2[r], iar[r],
                                  jx1, jy1, jx2, jy2, jar);
        u64 m0 = __ballot(h[0]);
        u64 m1 = __ballot(h[1]);
        u64 m2 = __ballot(h[2]);
        u64 m3 = __ballot(h[3]);
        if (lane < nr) {
            u64 mv = (lane == 0) ? m0 : (lane == 1) ? m1 : (lane == 2) ? m2 : m3;
            adj[(size_t)(i0 + lane) * W + k] = mv;
        }
    }
}

// ---------------------------------------------------------------------------
// Kernel D: single-wave sweep.
// FAST: rows in blocks of 32. All 64 loads of a block hoisted into registers
// (colb feeds the serial decision chain; rowb feeds lane-w's distributed
// suppression word). 32 branch-free register iterations per block; one
// __shfl per 64-row word boundary. SLOW fallback: on-the-fly IoU loop.
// ---------------------------------------------------------------------------
__global__ void __launch_bounds__(64) k_sweep(const int* __restrict__ counter,
        const float* __restrict__ ss,
        const float* __restrict__ sx1, const float* __restrict__ sy1,
        const float* __restrict__ sx2, const float* __restrict__ sy2,
        const u64* __restrict__ adj, long long cap_words,
        float* __restrict__ out)
{
    int M = *counter; if (M > NB) M = NB;
    int W = (M + 63) >> 6;
    int lane = threadIdx.x;

    if (fast_ok(M, cap_words)) {
        int wl = (lane < W) ? lane : 0;          // word this lane accumulates
        u64 sup = 0ull, mykw = 0ull, dec = 0ull;
        int nrb = (M + 31) >> 5;                 // 32-row blocks
        for (int rb = 0; rb < nrb; ++rb) {
            int base = rb << 5;
            int c = rb >> 1;                     // column-word of these rows
            if (!(rb & 1)) {
                // fresh word: lane c's accumulated suppression so far
                dec = (rb == 0) ? 0ull : (u64)__shfl((unsigned long long)sup, c);
            }
            int rem = M - (c << 6);              // tail-mask rows >= M
            if (rem < 64) dec |= (~0ull) << rem;
            u64 colb[32], rowb[32];
            #pragma unroll
            for (int t = 0; t < 32; ++t) {
                const u64* rp = adj + (size_t)(base + t) * W;
                colb[t] = rp[c];
                rowb[t] = rp[wl];
            }
            u64 kw = 0ull;
            int sh = (rb & 1) << 5;              // bit offset within word
            #pragma unroll
            for (int t = 0; t < 32; ++t) {
                u64 b = (dec >> (t + sh)) & 1ull;
                u64 m = b - 1ull;                // ~0 if kept, 0 if suppressed
                dec |= colb[t] & m;
                sup |= rowb[t] & m;
                kw  |= m & (1ull << t);
            }
            mykw |= (lane == c) ? (kw << sh) : 0ull;
        }
        // Emit kept rows: lane w owns word w -> i = (w<<6) + bit
        u64 kb = mykw;
        while (kb) {
            int t = __builtin_ctzll(kb);
            kb &= kb - 1ull;
            int i = (lane << 6) + t;
            float a = sx1[i], b = sy1[i], c = sx2[i], d = sy2[i];
            out[i * 5 + 0] = ss[i];
            out[i * 5 + 1] = a;
            out[i * 5 + 2] = b;
            out[i * 5 + 3] = __fsub_rn(c, a);
            out[i * 5 + 4] = __fsub_rn(d, b);
            out[5 * NB + i] = 1.0f;
        }
        return;
    }

    // ---------------- slow fallback (correct for any M <= NB) ----------------
    __shared__ float lx1[NMS_CAP], ly1[NMS_CAP], lx2[NMS_CAP], ly2[NMS_CAP], lar[NMS_CAP];
    for (int k = lane; k < M && k < NMS_CAP; k += 64) {
        float a = sx1[k], b = sy1[k], c = sx2[k], d = sy2[k];
        lx1[k] = a; ly1[k] = b; lx2[k] = c; ly2[k] = d;
        lar[k] = __fmul_rn(__fsub_rn(c, a), __fsub_rn(d, b));
    }
    __syncthreads();

    u64 kbs[3] = {0ull, 0ull, 0ull};
    for (int i = 0; i < M; ++i) {
        float ix1, iy1, ix2, iy2, iar;
        if (i < NMS_CAP) { ix1 = lx1[i]; iy1 = ly1[i]; ix2 = lx2[i]; iy2 = ly2[i]; iar = lar[i]; }
        else {
            ix1 = sx1[i]; iy1 = sy1[i]; ix2 = sx2[i]; iy2 = sy2[i];
            iar = __fmul_rn(__fsub_rn(ix2, ix1), __fsub_rn(iy2, iy1));
        }
        int hit = 0;
        int nk = (i > lane) ? ((i - lane + 63) >> 6) : 0;
        for (int w = 0; w < 3 && !hit; ++w) {
            int klim = nk - (w << 6);
            if (klim <= 0) break;
            u64 bits = kbs[w];
            if (klim < 64) bits &= ((1ull << klim) - 1ull);
            while (bits) {
                int kk = __builtin_ctzll(bits);
                bits &= bits - 1ull;
                int jj = lane + (((w << 6) + kk) << 6);
                float jx1, jy1, jx2, jy2, jar;
                if (jj < NMS_CAP) { jx1 = lx1[jj]; jy1 = ly1[jj]; jx2 = lx2[jj]; jy2 = ly2[jj]; jar = lar[jj]; }
                else {
                    jx1 = sx1[jj]; jy1 = sy1[jj]; jx2 = sx2[jj]; jy2 = sy2[jj];
                    jar = __fmul_rn(__fsub_rn(jx2, jx1), __fsub_rn(jy2, jy1));
                }
                if (iou_hit(ix1, iy1, ix2, iy2, iar, jx1, jy1, jx2, jy2, jar)) { hit = 1; break; }
            }
        }
        int suppressed = __any(hit);
        if (!suppressed && lane == (i & 63)) {
            int k = i >> 6;
            kbs[k >> 6] |= 1ull << (k & 63);
        }
    }
    for (int w = 0; w < 3; ++w) {
        u64 bits = kbs[w];
        while (bits) {
            int kk = __builtin_ctzll(bits);
            bits &= bits - 1ull;
            int jj = lane + (((w << 6) + kk) << 6);
            float a, b, c, d;
            if (jj < NMS_CAP) { a = lx1[jj]; b = ly1[jj]; c = lx2[jj]; d = ly2[jj]; }
            else { a = sx1[jj]; b = sy1[jj]; c = sx2[jj]; d = sy2[jj]; }
            out[jj * 5 + 0] = ss[jj];
            out[jj * 5 + 1] = a;
            out[jj * 5 + 2] = b;
            out[jj * 5 + 3] = __fsub_rn(c, a);
            out[jj * 5 + 4] = __fsub_rn(d, b);
            out[5 * NB + jj] = 1.0f;
        }
    }
}

extern "C" void kernel_launch(void* const* d_in, const int* in_sizes, int n_in,
                              void* d_out, int out_size, void* d_ws, size_t ws_size,
                              hipStream_t stream) {
    const float* x = (const float*)d_in[0];
    float* out = (float*)d_out;

    // Workspace layout (8-byte aligned throughout):
    // [0,16)      counter
    // ckey        u64[NB]
    // cx1..cy2    float[NB] x4   (compacted box coords)
    // ss,sx1..sy2 float[NB] x5   (sorted)
    // adj         u64 bit matrix
    char* ws = (char*)d_ws;
    int* counter = (int*)ws;
    u64* ckey = (u64*)(ws + 16);
    float* fbase = (float*)(ws + 16 + (size_t)8 * NB);
    float* cx1 = fbase + 0 * NB;
    float* cy1 = fbase + 1 * NB;
    float* cx2 = fbase + 2 * NB;
    float* cy2 = fbase + 3 * NB;
    float* ss  = fbase + 4 * NB;
    float* sx1 = fbase + 5 * NB;
    float* sy1 = fbase + 6 * NB;
    float* sx2 = fbase + 7 * NB;
    float* sy2 = fbase + 8 * NB;
    size_t adj_off = 16 + (size_t)8 * NB + (size_t)9 * NB * 4;   // 405,520 B
    u64* adj = (u64*)(ws + adj_off);
    long long cap_words = (ws_size > adj_off) ? (long long)((ws_size - adj_off) / 8) : 0;

    const int threads = 256;
    const int blocks = (NB + threads - 1) / threads;   // 36
    k_zero<<<64, 256, 0, stream>>>(out, out_size, counter);
    k_compute<<<blocks, threads, 0, stream>>>(x, counter, ckey, cx1, cy1, cx2, cy2);
    k_rank<<<blocks, threads, 0, stream>>>(counter, ckey, cx1, cy1, cx2, cy2,
                                           ss, sx1, sy1, sx2, sy2);
    k_adj<<<(NB + 3) / 4, 64, 0, stream>>>(counter, sx1, sy1, sx2, sy2, adj, cap_words);
    k_sweep<<<1, 64, 0, stream>>>(counter, ss, sx1, sy1, sx2, sy2, adj, cap_words, out);
}